// Round 8
// baseline (437.419 us; speedup 1.0000x reference)
//
#include <hip/hip_runtime.h>

#define SPB 5
#define TPB 256

__global__ __launch_bounds__(TPB, 2)
void conv4d_fused(const float* __restrict__ x,
                  const float* __restrict__ w1, const float* __restrict__ b1,
                  const float* __restrict__ w2, const float* __restrict__ b2,
                  float* __restrict__ out, int B)
{
    // s_x: phase-1 input [s][l*343 + d*49 + h*7 + w] (12005 floats),
    // then overlaid after phase 1 by h1 [s][o*625 + l*125 + d*25 + h*5 + w]
    // (6250 floats). Total LDS ~51.7 KB -> 3 blocks/CU.
    __shared__ float s_x[SPB * 2401];
    __shared__ float s_w1[162];
    __shared__ float s_w2[648];
    __shared__ float s_b1[2];
    __shared__ float s_b2[4];

    const int t  = threadIdx.x;
    const int s0 = blockIdx.x * SPB;
    const int ns = min(SPB, B - s0);

    // ---- stage weights + biases
    for (int i = t; i < 162; i += TPB) s_w1[i] = w1[i];
    for (int i = t; i < 648; i += TPB) s_w2[i] = w2[i];
    if (t < 2) s_b1[t] = b1[t];
    if (t < 4) s_b2[t] = b2[t];

    // ---- stage inputs (flat coalesced copy across the block's samples)
    {
        const float* xp = x + (size_t)s0 * 2401;
        const int n = ns * 2401;
        for (int i = t; i < n; i += TPB) s_x[i] = xp[i];
    }
    __syncthreads();

    // ---- phase 1 (o-merged): task = (s, l, d) -> BOTH channels' 5x5 plane
    //      in regs. 125 tasks/block = 2 waves, 98% packed. Each 7x7 patch is
    //      read ONCE and feeds 450 FMAs (2 channels x 225) -- patch-read
    //      instructions halved vs per-o tasks. FMA issue count unchanged.
    float acc[2][5][5];
    int h1b = 0;
    const bool act1 = t < ns * 25;
    if (act1) {
        int s = t / 25;
        int r = t % 25;
        int l = r / 5, d = r % 5;
        h1b = s * 1250 + l * 125 + d * 25;

        #pragma unroll
        for (int o = 0; o < 2; ++o) {
            const float bias = s_b1[o];
            #pragma unroll
            for (int h = 0; h < 5; ++h)
                #pragma unroll
                for (int w = 0; w < 5; ++w) acc[o][h][w] = bias;
        }

        const float* xs = s_x + s * 2401;
        #pragma unroll
        for (int kl = 0; kl < 3; ++kl)
        #pragma unroll
        for (int kd = 0; kd < 3; ++kd) {
            float p[7][7];
            const float* xp = xs + (l + kl) * 343 + (d + kd) * 49;
            #pragma unroll
            for (int i = 0; i < 49; ++i) p[i / 7][i % 7] = xp[i];
            #pragma unroll
            for (int o = 0; o < 2; ++o) {
                const float* wp = s_w1 + o * 81 + kl * 27 + kd * 9;
                #pragma unroll
                for (int kh = 0; kh < 3; ++kh)
                #pragma unroll
                for (int kw = 0; kw < 3; ++kw) {
                    const float wv = wp[kh * 3 + kw];
                    #pragma unroll
                    for (int h = 0; h < 5; ++h)
                    #pragma unroll
                    for (int w = 0; w < 5; ++w)
                        acc[o][h][w] += p[h + kh][w + kw] * wv;
                }
            }
        }
    }
    __syncthreads();   // all phase-1 reads of s_x complete -> region dead

    // ---- write h1 (ReLU) for both channels into the overlay
    if (act1) {
        #pragma unroll
        for (int o = 0; o < 2; ++o) {
            float* hp = s_x + h1b + o * 625;
            #pragma unroll
            for (int h = 0; h < 5; ++h)
            #pragma unroll
            for (int w = 0; w < 5; ++w)
                hp[h * 5 + w] = fmaxf(acc[o][h][w], 0.0f);
        }
    }
    __syncthreads();

    // ---- phase 2: task = (s, o2, l, d) -> full 3x3 (h,w) plane in regs.
    //      180/256 threads active (94% packed over 3 waves).
    if (t < ns * 36) {
        int s = t / 36;
        int r = t % 36;
        int o2 = r / 9; r %= 9;
        int l = r / 3, d = r % 3;

        float a2[3][3];
        const float bias = s_b2[o2];
        #pragma unroll
        for (int h = 0; h < 3; ++h)
            #pragma unroll
            for (int w = 0; w < 3; ++w) a2[h][w] = bias;

        #pragma unroll
        for (int c = 0; c < 2; ++c) {
            const float* hs = s_x + s * 1250 + c * 625;
            const float* wb = s_w2 + o2 * 162 + c * 81;
            #pragma unroll
            for (int kl = 0; kl < 3; ++kl)
            #pragma unroll
            for (int kd = 0; kd < 3; ++kd) {
                float p[5][5];
                const float* pp = hs + (l + kl) * 125 + (d + kd) * 25;
                #pragma unroll
                for (int i = 0; i < 25; ++i) p[i / 5][i % 5] = pp[i];
                const float* wp = wb + kl * 27 + kd * 9;
                #pragma unroll
                for (int kh = 0; kh < 3; ++kh)
                #pragma unroll
                for (int kw = 0; kw < 3; ++kw) {
                    const float wv = wp[kh * 3 + kw];
                    #pragma unroll
                    for (int h = 0; h < 3; ++h)
                    #pragma unroll
                    for (int w = 0; w < 3; ++w)
                        a2[h][w] += p[h + kh][w + kw] * wv;
                }
            }
        }
        float* op = out + (size_t)(s0 + s) * 324 + o2 * 81 + l * 27 + d * 9;
        #pragma unroll
        for (int h = 0; h < 3; ++h)
        #pragma unroll
        for (int w = 0; w < 3; ++w)
            op[h * 3 + w] = fmaxf(a2[h][w], 0.0f);
    }
}

extern "C" void kernel_launch(void* const* d_in, const int* in_sizes, int n_in,
                              void* d_out, int out_size, void* d_ws, size_t ws_size,
                              hipStream_t stream)
{
    const float* x  = (const float*)d_in[0];
    const float* w1 = (const float*)d_in[1];
    const float* b1 = (const float*)d_in[2];
    const float* w2 = (const float*)d_in[3];
    const float* b2 = (const float*)d_in[4];
    float* out = (float*)d_out;

    const int B = in_sizes[0] / 2401;          // 16384
    const int grid = (B + SPB - 1) / SPB;      // 3277 blocks
    conv4d_fused<<<grid, TPB, 0, stream>>>(x, w1, b1, w2, b2, out, B);
}

// Round 9
// 301.299 us; speedup vs baseline: 1.4518x; 1.4518x over previous
//
#include <hip/hip_runtime.h>

#define SPB 5
#define TPB 256

__global__ __launch_bounds__(TPB, 2)
void conv4d_fused(const float* __restrict__ x,
                  const float* __restrict__ w1, const float* __restrict__ b1,
                  const float* __restrict__ w2, const float* __restrict__ b2,
                  float* __restrict__ out, int B)
{
    // s_x: phase-1 input [s][l*343 + d*49 + h*7 + w] (12005 floats),
    // then overlaid after phase 1 by h1 [s][o*625 + l*125 + d*25 + h*5 + w]
    // (6250 floats). Total LDS ~51.7 KB -> 3 blocks/CU.
    __shared__ float s_x[SPB * 2401];
    __shared__ float s_w1[162];
    __shared__ float s_w2[648];
    __shared__ float s_b1[2];
    __shared__ float s_b2[4];

    const int t  = threadIdx.x;
    const int s0 = blockIdx.x * SPB;
    const int ns = min(SPB, B - s0);

    // ---- stage weights + biases
    for (int i = t; i < 162; i += TPB) s_w1[i] = w1[i];
    for (int i = t; i < 648; i += TPB) s_w2[i] = w2[i];
    if (t < 2) s_b1[t] = b1[t];
    if (t < 4) s_b2[t] = b2[t];

    // ---- stage inputs (flat coalesced copy across the block's samples)
    {
        const float* xp = x + (size_t)s0 * 2401;
        const int n = ns * 2401;
        for (int i = t; i < n; i += TPB) s_x[i] = xp[i];
    }
    __syncthreads();

    // ---- phase 1 (o-merged, ROW-STREAMED): task = (s, l, d) -> both
    //      channels' 5x5 plane in regs. Each 7x7 patch row (7 floats) is
    //      read once and immediately consumed by every (kh,o,kw) tap that
    //      needs it, then dead. Live set ~= acc(50) + row(7) + wv(18),
    //      safely under the 102-VGPR occupancy boundary (R8's full-patch
    //      version clamped at 128 and spilled ~250 B/thread).
    float acc[2][5][5];
    int h1b = 0;
    const bool act1 = t < ns * 25;
    if (act1) {
        int s = t / 25;
        int r = t % 25;
        int l = r / 5, d = r % 5;
        h1b = s * 1250 + l * 125 + d * 25;

        #pragma unroll
        for (int o = 0; o < 2; ++o) {
            const float bias = s_b1[o];
            #pragma unroll
            for (int h = 0; h < 5; ++h)
                #pragma unroll
                for (int w = 0; w < 5; ++w) acc[o][h][w] = bias;
        }

        const float* xs = s_x + s * 2401;
        #pragma unroll
        for (int kl = 0; kl < 3; ++kl)
        #pragma unroll
        for (int kd = 0; kd < 3; ++kd) {
            // 18 (h,w)-tap weights for this (kl,kd), both channels
            float wv[2][9];
            #pragma unroll
            for (int o = 0; o < 2; ++o)
                #pragma unroll
                for (int k = 0; k < 9; ++k)
                    wv[o][k] = s_w1[o * 81 + kl * 27 + kd * 9 + k];

            const float* xp = xs + (l + kl) * 343 + (d + kd) * 49;
            #pragma unroll
            for (int i = 0; i < 7; ++i) {
                float row[7];
                #pragma unroll
                for (int j = 0; j < 7; ++j) row[j] = xp[i * 7 + j];
                #pragma unroll
                for (int kh = 0; kh < 3; ++kh) {
                    const int h = i - kh;          // compile-time after unroll
                    if (h >= 0 && h <= 4) {
                        #pragma unroll
                        for (int o = 0; o < 2; ++o)
                        #pragma unroll
                        for (int kw = 0; kw < 3; ++kw) {
                            const float wvv = wv[o][kh * 3 + kw];
                            #pragma unroll
                            for (int w = 0; w < 5; ++w)
                                acc[o][h][w] += row[w + kw] * wvv;
                        }
                    }
                }
            }
        }
    }
    __syncthreads();   // all phase-1 reads of s_x complete -> region dead

    // ---- write h1 (ReLU) for both channels into the overlay
    if (act1) {
        #pragma unroll
        for (int o = 0; o < 2; ++o) {
            float* hp = s_x + h1b + o * 625;
            #pragma unroll
            for (int h = 0; h < 5; ++h)
            #pragma unroll
            for (int w = 0; w < 5; ++w)
                hp[h * 5 + w] = fmaxf(acc[o][h][w], 0.0f);
        }
    }
    __syncthreads();

    // ---- phase 2: task = (s, o2, l, d) -> full 3x3 (h,w) plane in regs.
    //      180/256 threads active.
    if (t < ns * 36) {
        int s = t / 36;
        int r = t % 36;
        int o2 = r / 9; r %= 9;
        int l = r / 3, d = r % 3;

        float a2[3][3];
        const float bias = s_b2[o2];
        #pragma unroll
        for (int h = 0; h < 3; ++h)
            #pragma unroll
            for (int w = 0; w < 3; ++w) a2[h][w] = bias;

        #pragma unroll
        for (int c = 0; c < 2; ++c) {
            const float* hs = s_x + s * 1250 + c * 625;
            const float* wb = s_w2 + o2 * 162 + c * 81;
            #pragma unroll
            for (int kl = 0; kl < 3; ++kl)
            #pragma unroll
            for (int kd = 0; kd < 3; ++kd) {
                float p[5][5];
                const float* pp = hs + (l + kl) * 125 + (d + kd) * 25;
                #pragma unroll
                for (int i = 0; i < 25; ++i) p[i / 5][i % 5] = pp[i];
                const float* wp = wb + kl * 27 + kd * 9;
                #pragma unroll
                for (int kh = 0; kh < 3; ++kh)
                #pragma unroll
                for (int kw = 0; kw < 3; ++kw) {
                    const float wv = wp[kh * 3 + kw];
                    #pragma unroll
                    for (int h = 0; h < 3; ++h)
                    #pragma unroll
                    for (int w = 0; w < 3; ++w)
                        a2[h][w] += p[h + kh][w + kw] * wv;
                }
            }
        }
        float* op = out + (size_t)(s0 + s) * 324 + o2 * 81 + l * 27 + d * 9;
        #pragma unroll
        for (int h = 0; h < 3; ++h)
        #pragma unroll
        for (int w = 0; w < 3; ++w)
            op[h * 3 + w] = fmaxf(a2[h][w], 0.0f);
    }
}

extern "C" void kernel_launch(void* const* d_in, const int* in_sizes, int n_in,
                              void* d_out, int out_size, void* d_ws, size_t ws_size,
                              hipStream_t stream)
{
    const float* x  = (const float*)d_in[0];
    const float* w1 = (const float*)d_in[1];
    const float* b1 = (const float*)d_in[2];
    const float* w2 = (const float*)d_in[3];
    const float* b2 = (const float*)d_in[4];
    float* out = (float*)d_out;

    const int B = in_sizes[0] / 2401;          // 16384
    const int grid = (B + SPB - 1) / SPB;      // 3277 blocks
    conv4d_fused<<<grid, TPB, 0, stream>>>(x, w1, b1, w2, b2, out, B);
}

// Round 10
// 290.456 us; speedup vs baseline: 1.5060x; 1.0373x over previous
//
#include <hip/hip_runtime.h>

#define SPB 5
#define TPB 256
// x: padded plane stride 50 (49->50, 8B-aligned bases), sample stride 49*50
#define XPL 50
#define XSS 2450
// h1 overlay: padded plane stride 26, strides d:26 l:130 o:650 s:1300
#define H1PL 26
#define H1L  130
#define H1O  650
#define H1S  1300

__global__ __launch_bounds__(TPB, 2)
void conv4d_fused(const float* __restrict__ x,
                  const float* __restrict__ w1, const float* __restrict__ b1,
                  const float* __restrict__ w2, const float* __restrict__ b2,
                  float* __restrict__ out, int B)
{
    // s_x: phase-1 input [s][plane(7*7)][50] = 12250 floats, overlaid after
    // phase 1 by h1 [s][o][l][d][26] = 6500 floats. ~52.3 KB -> 3 blocks/CU.
    __shared__ __align__(8) float s_x[SPB * XSS];
    __shared__ float s_w1[162];
    __shared__ float s_w2[648];
    __shared__ float s_b1[2];
    __shared__ float s_b2[4];

    const int t  = threadIdx.x;
    const int s0 = blockIdx.x * SPB;
    const int ns = min(SPB, B - s0);

    // ---- stage weights + biases
    for (int i = t; i < 162; i += TPB) s_w1[i] = w1[i];
    for (int i = t; i < 648; i += TPB) s_w2[i] = w2[i];
    if (t < 2) s_b1[t] = b1[t];
    if (t < 4) s_b2[t] = b2[t];

    // ---- stage x with plane padding 49->50 (pads never read)
    {
        const float* xp = x + (size_t)s0 * 2401;
        const int n = ns * 2401;
        for (int i = t; i < n; i += TPB) {
            unsigned pl = (unsigned)i / 49u;        // s*49 + plane
            unsigned c  = (unsigned)i - pl * 49u;
            s_x[pl * XPL + c] = xp[i];
        }
    }
    __syncthreads();

    // ---- phase 1: task = (s, o, l, d) -> full 5x5 plane in regs.
    //      250/256 threads, 4 waves (R6's proven structure). Patch reads are
    //      ds_read_b64: 24 pairs + 1 scalar per 49-float patch (was 49 b32).
    float acc[5][5];
    int h1b = 0;
    const bool act1 = t < ns * 50;
    if (act1) {
        int s = t / 50;
        int r = t % 50;
        int o = r / 25; r %= 25;
        int l = r / 5, d = r % 5;
        h1b = s * H1S + o * H1O + l * H1L + d * H1PL;

        const float bias = s_b1[o];
        #pragma unroll
        for (int h = 0; h < 5; ++h)
            #pragma unroll
            for (int w = 0; w < 5; ++w) acc[h][w] = bias;

        const float* xs = s_x + s * XSS;
        const float* wo = s_w1 + o * 81;
        #pragma unroll
        for (int kl = 0; kl < 3; ++kl)
        #pragma unroll
        for (int kd = 0; kd < 3; ++kd) {
            float p[49];
            const float* xp = xs + ((l + kl) * 7 + (d + kd)) * XPL; // even idx
            const float2* q = (const float2*)xp;
            #pragma unroll
            for (int i = 0; i < 24; ++i) {
                const float2 f = q[i];
                p[2 * i] = f.x; p[2 * i + 1] = f.y;
            }
            p[48] = xp[48];
            const float* wp = wo + kl * 27 + kd * 9;
            #pragma unroll
            for (int kh = 0; kh < 3; ++kh)
            #pragma unroll
            for (int kw = 0; kw < 3; ++kw) {
                const float wv = wp[kh * 3 + kw];
                #pragma unroll
                for (int h = 0; h < 5; ++h)
                #pragma unroll
                for (int w = 0; w < 5; ++w)
                    acc[h][w] += p[(h + kh) * 7 + (w + kw)] * wv;
            }
        }
    }
    __syncthreads();   // all phase-1 reads of s_x complete -> region dead

    // ---- write h1 (ReLU) into overlay as float2 (base even)
    if (act1) {
        float* hp = s_x + h1b;
        #pragma unroll
        for (int i = 0; i < 12; ++i) {
            float2 f;
            f.x = fmaxf(acc[(2 * i) / 5][(2 * i) % 5], 0.0f);
            f.y = fmaxf(acc[(2 * i + 1) / 5][(2 * i + 1) % 5], 0.0f);
            ((float2*)hp)[i] = f;
        }
        hp[24] = fmaxf(acc[4][4], 0.0f);
    }
    __syncthreads();

    // ---- phase 2: task = (s, o2, l, d) -> full 3x3 plane in regs.
    //      180/256 threads. h1 plane reads are 12 x b64 + 1 (was 25 b32).
    if (t < ns * 36) {
        int s = t / 36;
        int r = t % 36;
        int o2 = r / 9; r %= 9;
        int l = r / 3, d = r % 3;

        float a2[3][3];
        const float bias = s_b2[o2];
        #pragma unroll
        for (int h = 0; h < 3; ++h)
            #pragma unroll
            for (int w = 0; w < 3; ++w) a2[h][w] = bias;

        #pragma unroll
        for (int c = 0; c < 2; ++c) {
            const float* hs = s_x + s * H1S + c * H1O;
            const float* wb = s_w2 + o2 * 162 + c * 81;
            #pragma unroll
            for (int kl = 0; kl < 3; ++kl)
            #pragma unroll
            for (int kd = 0; kd < 3; ++kd) {
                float p[25];
                const float* pp = hs + (l + kl) * H1L + (d + kd) * H1PL; // even
                const float2* q = (const float2*)pp;
                #pragma unroll
                for (int i = 0; i < 12; ++i) {
                    const float2 f = q[i];
                    p[2 * i] = f.x; p[2 * i + 1] = f.y;
                }
                p[24] = pp[24];
                const float* wp = wb + kl * 27 + kd * 9;
                #pragma unroll
                for (int kh = 0; kh < 3; ++kh)
                #pragma unroll
                for (int kw = 0; kw < 3; ++kw) {
                    const float wv = wp[kh * 3 + kw];
                    #pragma unroll
                    for (int h = 0; h < 3; ++h)
                    #pragma unroll
                    for (int w = 0; w < 3; ++w)
                        a2[h][w] += p[(h + kh) * 5 + (w + kw)] * wv;
                }
            }
        }
        float* op = out + (size_t)(s0 + s) * 324 + o2 * 81 + l * 27 + d * 9;
        #pragma unroll
        for (int h = 0; h < 3; ++h)
        #pragma unroll
        for (int w = 0; w < 3; ++w)
            op[h * 3 + w] = fmaxf(a2[h][w], 0.0f);
    }
}

extern "C" void kernel_launch(void* const* d_in, const int* in_sizes, int n_in,
                              void* d_out, int out_size, void* d_ws, size_t ws_size,
                              hipStream_t stream)
{
    const float* x  = (const float*)d_in[0];
    const float* w1 = (const float*)d_in[1];
    const float* b1 = (const float*)d_in[2];
    const float* w2 = (const float*)d_in[3];
    const float* b2 = (const float*)d_in[4];
    float* out = (float*)d_out;

    const int B = in_sizes[0] / 2401;          // 16384
    const int grid = (B + SPB - 1) / SPB;      // 3277 blocks
    conv4d_fused<<<grid, TPB, 0, stream>>>(x, w1, b1, w2, b2, out, B);
}